// Round 7
// baseline (328.940 us; speedup 1.0000x reference)
//
#include <hip/hip_runtime.h>
#include <hip/hip_bf16.h>

// B=2, S=2048, IN=1024, H=16, D=64 MHA forward.
// wconv ; maskpack ; cvt3 (QKV fp32->bf16) ; gemm_qkv (bf16, fused z=0..2) ;
// attn (flash, no-max softmax, global_load_lds dbuf K/V, XOR-swizzle, bitmask) ;
// gemm_out (+residual).

#define BB   2
#define SS   2048
#define IND  1024
#define HH   16
#define DD   64
#define MM_ELEMS 524288   // 4096*1024/8 eight-element chunks per tensor

typedef __attribute__((ext_vector_type(8))) short  s8b;    // 8 x bf16 MFMA A/B frag
typedef __attribute__((ext_vector_type(4))) short  s4b;    // 4 x bf16
typedef __attribute__((ext_vector_type(4))) float  f32x4;  // MFMA C/D frag

static __device__ __forceinline__ short f2b(float x) {
    return __builtin_bit_cast(short, __float2bfloat16(x));
}

// async global->LDS, 16B per lane; LDS dest = base + lane*16 (wave-uniform base)
#define GLD16(g, l)                                                             \
    __builtin_amdgcn_global_load_lds(                                           \
        (const __attribute__((address_space(1))) unsigned int*)(g),             \
        (__attribute__((address_space(3))) unsigned int*)(l), 16, 0, 0)

// ---------------------------------------------------------------------------
// Kernel 1: weights fp32 [K][N] -> bf16 W^T [N][K].  z==0 (Wq) scaled by 1/8.
// ---------------------------------------------------------------------------
__global__ __launch_bounds__(256) void wconv(const float* __restrict__ w0,
                                             const float* __restrict__ w1,
                                             const float* __restrict__ w2,
                                             const float* __restrict__ w3,
                                             short* __restrict__ out) {
    const int z = blockIdx.z;
    const float* src = (z == 0) ? w0 : (z == 1) ? w1 : (z == 2) ? w2 : w3;
    const float wscale = (z == 0) ? 0.125f : 1.0f;
    short* dst = out + (size_t)z * IND * IND;
    __shared__ __attribute__((aligned(16))) short ls[64][72];
    const int t  = threadIdx.x;
    const int k0 = blockIdx.y * 64;
    const int n0 = blockIdx.x * 64;
#pragma unroll
    for (int p = 0; p < 4; ++p) {
        int ch = t + p * 256;
        int r  = ch >> 4;
        int c4 = ch & 15;
        float4 v = *reinterpret_cast<const float4*>(&src[(size_t)(k0 + r) * IND + n0 + c4 * 4]);
        ls[r][c4 * 4 + 0] = f2b(v.x * wscale);
        ls[r][c4 * 4 + 1] = f2b(v.y * wscale);
        ls[r][c4 * 4 + 2] = f2b(v.z * wscale);
        ls[r][c4 * 4 + 3] = f2b(v.w * wscale);
    }
    __syncthreads();
#pragma unroll
    for (int p = 0; p < 2; ++p) {
        int ch = t + p * 256;
        int nr = ch >> 3;
        int kg = ch & 7;
        s8b o;
#pragma unroll
        for (int j = 0; j < 8; ++j) o[j] = ls[kg * 8 + j][nr];
        *reinterpret_cast<s8b*>(&dst[(size_t)(n0 + nr) * IND + k0 + kg * 8]) = o;
    }
}

// ---------------------------------------------------------------------------
// Kernel 2: pack mask [B,S,S] (bool or int32, runtime-detected) into bits.
// ---------------------------------------------------------------------------
__global__ __launch_bounds__(256) void maskpack(const unsigned char* __restrict__ mask,
                                                unsigned long long* __restrict__ bits) {
    __shared__ int s_flag;
    const int t = threadIdx.x;
    if (t == 0) s_flag = 0;
    __syncthreads();
    {
        int bad = 0;
#pragma unroll
        for (int i = 0; i < 16; ++i) {
            int idx = t * 16 + i;
            if ((idx & 3) && mask[idx]) bad = 1;
        }
        if (bad) s_flag = 1;
    }
    __syncthreads();
    const bool isI32 = (s_flag == 0);

    const int lane = t & 63;
    const size_t nwords = (size_t)BB * SS * SS / 64;            // 131072
    size_t w = (size_t)blockIdx.x * 4 + (t >> 6);
    const size_t stride = (size_t)gridDim.x * 4;
    if (isI32) {
        const unsigned* m4 = (const unsigned*)mask;
        for (; w < nwords; w += stride) {
            unsigned long long bal = __ballot(m4[w * 64 + lane] != 0);
            if (lane == 0) bits[w] = bal;
        }
    } else {
        for (; w < nwords; w += stride) {
            unsigned long long bal = __ballot(mask[w * 64 + lane] != 0);
            if (lane == 0) bits[w] = bal;
        }
    }
}

// ---------------------------------------------------------------------------
// Kernel 2b: Q,K,V fp32 -> bf16 [3][4096][1024] (one pass, vectorized).
// ---------------------------------------------------------------------------
__global__ __launch_bounds__(256) void cvt3(const float* __restrict__ q,
                                            const float* __restrict__ k,
                                            const float* __restrict__ v,
                                            short* __restrict__ o) {
    const size_t nchunk = (size_t)3 * MM_ELEMS;
    size_t i = (size_t)blockIdx.x * 256 + threadIdx.x;
    const size_t stride = (size_t)gridDim.x * 256;
    for (; i < nchunk; i += stride) {
        size_t base = i * 8;
        int z = (int)(base >> 22);                       // 4M elems per tensor
        size_t off = base & 4194303u;
        const float* src = (z == 0) ? q : (z == 1) ? k : v;
        float4 a = *reinterpret_cast<const float4*>(&src[off]);
        float4 b = *reinterpret_cast<const float4*>(&src[off + 4]);
        s8b w;
        w[0] = f2b(a.x); w[1] = f2b(a.y); w[2] = f2b(a.z); w[3] = f2b(a.w);
        w[4] = f2b(b.x); w[5] = f2b(b.y); w[6] = f2b(b.z); w[7] = f2b(b.w);
        *reinterpret_cast<s8b*>(&o[base]) = w;
    }
}

// ---------------------------------------------------------------------------
// Kernel 3: fused QKV projection GEMM (all-bf16).  grid (8,32,3).
// C[4096][1024] = A * Wt^T ; z<2 -> bf16 [B,H,S,D] (q,k) ; z==2 -> [B,H,D,S] (v).
// ---------------------------------------------------------------------------
__global__ __launch_bounds__(256) void gemm_qkv(const short* __restrict__ abf,
                                                const short* __restrict__ wt,
                                                short* __restrict__ qb,
                                                short* __restrict__ kb,
                                                short* __restrict__ vt) {
    __shared__ __attribute__((aligned(16))) short lsA[128 * 40];
    __shared__ __attribute__((aligned(16))) short lsB[128 * 40];
    const int z = blockIdx.z;
    const short* A  = abf + (size_t)z * 4194304;
    const short* Bt = wt + (size_t)z * IND * IND;

    const int t    = threadIdx.x;
    const int lane = t & 63;
    const int wv   = t >> 6;
    const int wr   = wv >> 1, wc = wv & 1;
    const int m0   = blockIdx.y * 128, n0 = blockIdx.x * 128;
    const int lr   = lane & 15;
    const int lg   = lane >> 4;

    f32x4 acc[4][4] = {};

    for (int k0 = 0; k0 < IND; k0 += 32) {
        __syncthreads();
#pragma unroll
        for (int p = 0; p < 2; ++p) {
            int ch = t + p * 256;
            int r = ch >> 2, c8 = ch & 3;
            s8b v = *reinterpret_cast<const s8b*>(&A[(size_t)(m0 + r) * IND + k0 + c8 * 8]);
            *reinterpret_cast<s8b*>(&lsA[r * 40 + c8 * 8]) = v;
        }
#pragma unroll
        for (int p = 0; p < 2; ++p) {
            int ch = t + p * 256;
            int r = ch >> 2, c8 = ch & 3;
            s8b v = *reinterpret_cast<const s8b*>(&Bt[(size_t)(n0 + r) * IND + k0 + c8 * 8]);
            *reinterpret_cast<s8b*>(&lsB[r * 40 + c8 * 8]) = v;
        }
        __syncthreads();

        s8b af[4], bfr[4];
#pragma unroll
        for (int mi = 0; mi < 4; ++mi)
            af[mi] = *reinterpret_cast<const s8b*>(&lsA[(wr * 64 + mi * 16 + lr) * 40 + lg * 8]);
#pragma unroll
        for (int nj = 0; nj < 4; ++nj)
            bfr[nj] = *reinterpret_cast<const s8b*>(&lsB[(wc * 64 + nj * 16 + lr) * 40 + lg * 8]);
#pragma unroll
        for (int mi = 0; mi < 4; ++mi)
#pragma unroll
            for (int nj = 0; nj < 4; ++nj)
                acc[mi][nj] = __builtin_amdgcn_mfma_f32_16x16x32_bf16(af[mi], bfr[nj], acc[mi][nj], 0, 0, 0);
    }

#pragma unroll
    for (int mi = 0; mi < 4; ++mi) {
#pragma unroll
        for (int nj = 0; nj < 4; ++nj) {
            const int mbase = m0 + wr * 64 + mi * 16 + lg * 4;
            const int n     = n0 + wc * 64 + nj * 16 + lr;
            if (z < 2) {
                short* o = z ? kb : qb;
                const int h = n >> 6, d = n & 63;
#pragma unroll
                for (int i = 0; i < 4; ++i) {
                    int m = mbase + i;
                    int b = m >> 11, s = m & 2047;
                    o[((size_t)(b * HH + h) * SS + s) * DD + d] = f2b(acc[mi][nj][i]);
                }
            } else {
                const int b = mbase >> 11, sbase = mbase & 2047;
                const int h = n >> 6, d = n & 63;
                s4b w;
#pragma unroll
                for (int i = 0; i < 4; ++i) w[i] = f2b(acc[mi][nj][i]);
                *reinterpret_cast<s4b*>(&vt[((size_t)(b * HH + h) * DD + d) * SS + sbase]) = w;
            }
        }
    }
}

// ---------------------------------------------------------------------------
// Kernel 4: flash attention.  grid (S/64, B*H), 4 waves x 16 q-rows, KV 64.
// K/V staged via global_load_lds (16B) into double-buffered linear [64][64]
// LDS with XOR-swizzle: source col = (lane&7)^(lane>>3); read slot = lg^(row&7).
// One barrier per tile; next-tile loads issued right after it (latency hidden).
// No-max softmax (scale folded into Wq); rowsum via ones-MFMA; bitmask.
// ---------------------------------------------------------------------------
__global__ __launch_bounds__(256) void attn(const short* __restrict__ qb,
                                            const short* __restrict__ kb,
                                            const short* __restrict__ vt,
                                            const unsigned* __restrict__ mbw,
                                            short* __restrict__ ctx) {
    __shared__ __attribute__((aligned(16))) short lsK[2][64 * 64];
    __shared__ __attribute__((aligned(16))) short lsV[2][64 * 64];
    __shared__ __attribute__((aligned(16))) short lsP[4][16 * 72];

    const int t    = threadIdx.x;
    const int lane = t & 63;
    const int wv   = t >> 6;
    const int bh   = blockIdx.y;
    const int b    = bh >> 4, h = bh & 15;
    const int q0   = blockIdx.x * 64 + wv * 16;
    const int lr   = lane & 15;
    const int lg   = lane >> 4;

    const unsigned sel0 = 1u << lr;
    const unsigned sel1 = sel0 << 16;
    const uint2* mrp = (const uint2*)(mbw + (size_t)(b * SS + q0 + lg * 4) * (SS / 32));

    // staging geometry: lane -> row rk, swizzled source slot ck
    const int rk = lane >> 3;                 // 0..7
    const int ck = (lane & 7) ^ rk;           // pre-swizzled global column slot
    const short* kbase = kb + (size_t)bh * SS * DD;
    const short* vbase = vt + (size_t)bh * DD * SS;

    s8b aq[2];
#pragma unroll
    for (int ks = 0; ks < 2; ++ks)
        aq[ks] = *reinterpret_cast<const s8b*>(&qb[((size_t)bh * SS + q0 + lr) * DD + ks * 32 + lg * 8]);

    s8b ones;
#pragma unroll
    for (int j = 0; j < 8; ++j) ones[j] = (short)0x3F80;   // bf16 1.0

    f32x4 o[4] = {};
    float lrow[4] = {0.f, 0.f, 0.f, 0.f};

    // prologue: stage tile 0 into buffer 0 (each wave: 2 K-chunks + 2 V-chunks)
#pragma unroll
    for (int c = 0; c < 2; ++c) {
        int chunk = wv + c * 4;               // 0..7 ; 8 rows x 128B per chunk
        int row = chunk * 8 + rk;
        GLD16(&kbase[(size_t)row * DD + ck * 8], &lsK[0][chunk * 512]);
        GLD16(&vbase[(size_t)row * SS + ck * 8], &lsV[0][chunk * 512]);
    }

    int cur = 0;
    for (int kk0 = 0; kk0 < SS; kk0 += 64) {
        uint2 mw[4];
#pragma unroll
        for (int i = 0; i < 4; ++i) mw[i] = mrp[i * 32 + (kk0 >> 6)];

        __syncthreads();   // drains vmcnt -> buf[cur] ready; buf[cur^1] free

        if (kk0 + 64 < SS) {
#pragma unroll
            for (int c = 0; c < 2; ++c) {
                int chunk = wv + c * 4;
                int row = chunk * 8 + rk;
                GLD16(&kbase[(size_t)(kk0 + 64 + row) * DD + ck * 8], &lsK[cur ^ 1][chunk * 512]);
                GLD16(&vbase[(size_t)row * SS + kk0 + 64 + ck * 8], &lsV[cur ^ 1][chunk * 512]);
            }
        }

        const short* Kc = lsK[cur];
        const short* Vc = lsV[cur];

        // S = Q K^T (pre-scaled); swizzled B-frag reads (conflict-free)
        f32x4 sc[4];
#pragma unroll
        for (int nj = 0; nj < 4; ++nj) {
            const int R  = nj * 16 + lr;
            const int sw = R & 7;
            s8b bk0 = *reinterpret_cast<const s8b*>(&Kc[R * 64 + ((lg ^ sw) << 3)]);
            s8b bk1 = *reinterpret_cast<const s8b*>(&Kc[R * 64 + (((lg ^ 4) ^ sw) << 3)]);
            f32x4 zz = {};
            zz     = __builtin_amdgcn_mfma_f32_16x16x32_bf16(aq[0], bk0, zz, 0, 0, 0);
            sc[nj] = __builtin_amdgcn_mfma_f32_16x16x32_bf16(aq[1], bk1, zz, 0, 0, 0);
        }

        // P = masked ? 0 : exp(S) -> per-wave LDS
#pragma unroll
        for (int nj = 0; nj < 4; ++nj) {
            const unsigned slm = (nj & 1) ? sel1 : sel0;
#pragma unroll
            for (int i = 0; i < 4; ++i) {
                unsigned w = (nj < 2) ? mw[i].x : mw[i].y;
                float e = __expf(sc[nj][i]);
                float p = (w & slm) ? 0.f : e;
                lsP[wv][(lg * 4 + i) * 72 + nj * 16 + lr] = f2b(p);
            }
        }

        s8b pa[2];
#pragma unroll
        for (int ks = 0; ks < 2; ++ks)
            pa[ks] = *reinterpret_cast<const s8b*>(&lsP[wv][lr * 72 + ks * 32 + lg * 8]);

        // row-sum of P via ones-MFMA
        f32x4 rs = {};
        rs = __builtin_amdgcn_mfma_f32_16x16x32_bf16(pa[0], ones, rs, 0, 0, 0);
        rs = __builtin_amdgcn_mfma_f32_16x16x32_bf16(pa[1], ones, rs, 0, 0, 0);

#pragma unroll
        for (int nj = 0; nj < 4; ++nj) {
            const int R  = nj * 16 + lr;
            const int sw = R & 7;
            s8b bv0 = *reinterpret_cast<const s8b*>(&Vc[R * 64 + ((lg ^ sw) << 3)]);
            s8b bv1 = *reinterpret_cast<const s8b*>(&Vc[R * 64 + (((lg ^ 4) ^ sw) << 3)]);
            o[nj] = __builtin_amdgcn_mfma_f32_16x16x32_bf16(pa[0], bv0, o[nj], 0, 0, 0);
            o[nj] = __builtin_amdgcn_mfma_f32_16x16x32_bf16(pa[1], bv1, o[nj], 0, 0, 0);
        }
#pragma unroll
        for (int i = 0; i < 4; ++i) lrow[i] += rs[i];

        cur ^= 1;
    }

    float inv[4];
#pragma unroll
    for (int i = 0; i < 4; ++i) inv[i] = 1.0f / lrow[i];
#pragma unroll
    for (int nj = 0; nj < 4; ++nj)
#pragma unroll
        for (int i = 0; i < 4; ++i) {
            int q = q0 + lg * 4 + i;
            ctx[((size_t)(b * SS + q)) * (HH * DD) + h * DD + nj * 16 + lr] = f2b(o[nj][i] * inv[i]);
        }
}

// ---------------------------------------------------------------------------
// Kernel 5: out = ctx @ Wo^T + Q.  64x128 tile, 4 waves 2x2, 2x4 frags.
// ---------------------------------------------------------------------------
__global__ __launch_bounds__(256) void gemm_out(const short* __restrict__ Actx,
                                                const short* __restrict__ Bt,
                                                const float* __restrict__ resid,
                                                float* __restrict__ outp) {
    __shared__ __attribute__((aligned(16))) short lsA[64 * 40];
    __shared__ __attribute__((aligned(16))) short lsB[128 * 40];
    const int t    = threadIdx.x;
    const int lane = t & 63;
    const int wv   = t >> 6;
    const int wr   = wv >> 1, wc = wv & 1;
    const int m0   = blockIdx.y * 64, n0 = blockIdx.x * 128;
    const int lr   = lane & 15;
    const int lg   = lane >> 4;

    f32x4 acc[2][4] = {};

    for (int k0 = 0; k0 < IND; k0 += 32) {
        __syncthreads();
        {
            int r = t >> 2, c8 = t & 3;
            s8b v = *reinterpret_cast<const s8b*>(&Actx[(size_t)(m0 + r) * IND + k0 + c8 * 8]);
            *reinterpret_cast<s8b*>(&lsA[r * 40 + c8 * 8]) = v;
        }
#pragma unroll
        for (int p = 0; p < 2; ++p) {
            int ch = t + p * 256;
            int r = ch >> 2, c8 = ch & 3;
            s8b v = *reinterpret_cast<const s8b*>(&Bt[(size_t)(n0 + r) * IND + k0 + c8 * 8]);
            *reinterpret_cast<s8b*>(&lsB[r * 40 + c8 * 8]) = v;
        }
        __syncthreads();

        s8b af[2], bfr[4];
#pragma unroll
        for (int mi = 0; mi < 2; ++mi)
            af[mi] = *reinterpret_cast<const s8b*>(&lsA[(wr * 32 + mi * 16 + lr) * 40 + lg * 8]);
#pragma unroll
        for (int nj = 0; nj < 4; ++nj)
            bfr[nj] = *reinterpret_cast<const s8b*>(&lsB[(wc * 64 + nj * 16 + lr) * 40 + lg * 8]);
#pragma unroll
        for (int mi = 0; mi < 2; ++mi)
#pragma unroll
            for (int nj = 0; nj < 4; ++nj)
                acc[mi][nj] = __builtin_amdgcn_mfma_f32_16x16x32_bf16(af[mi], bfr[nj], acc[mi][nj], 0, 0, 0);
    }

#pragma unroll
    for (int mi = 0; mi < 2; ++mi)
#pragma unroll
        for (int nj = 0; nj < 4; ++nj) {
            const int mbase = m0 + wr * 32 + mi * 16 + lg * 4;
            const int n     = n0 + wc * 64 + nj * 16 + lr;
#pragma unroll
            for (int i = 0; i < 4; ++i) {
                int m = mbase + i;
                outp[(size_t)m * IND + n] = acc[mi][nj][i] + resid[(size_t)m * IND + n];
            }
        }
}

// ---------------------------------------------------------------------------
extern "C" void kernel_launch(void* const* d_in, const int* in_sizes, int n_in,
                              void* d_out, int out_size, void* d_ws, size_t ws_size,
                              hipStream_t stream) {
    const float* Qin = (const float*)d_in[0];
    const float* Kin = (const float*)d_in[1];
    const float* Vin = (const float*)d_in[2];
    const unsigned char* mask = (const unsigned char*)d_in[3];
    const float* Wq = (const float*)d_in[4];
    const float* Wk = (const float*)d_in[5];
    const float* Wv = (const float*)d_in[6];
    const float* Wo = (const float*)d_in[7];

    char* ws = (char*)d_ws;
    const size_t WSZ = (size_t)IND * IND;
    short* wt  = (short*)ws;                                       // 8 MB (4x W^T bf16)
    short* qb  = (short*)(ws + 8ull  * 1024 * 1024);               // [B,H,S,D]
    short* kb  = (short*)(ws + 16ull * 1024 * 1024);               // [B,H,S,D]
    short* vt  = (short*)(ws + 24ull * 1024 * 1024);               // [B,H,D,S]
    unsigned long long* mbits = (unsigned long long*)(ws + 32ull * 1024 * 1024);  // 1 MB
    short* abf = (short*)(ws + 36ull * 1024 * 1024);               // 24 MB bf16 QKV inputs
    short* ctx = (short*)(ws + 36ull * 1024 * 1024);               // overlaps abf (abf dead when attn writes ctx)

    wconv   <<<dim3(16, 16, 4), 256, 0, stream>>>(Wq, Wk, Wv, Wo, wt);
    maskpack<<<512, 256, 0, stream>>>(mask, mbits);
    cvt3    <<<2048, 256, 0, stream>>>(Qin, Kin, Vin, abf);
    gemm_qkv<<<dim3(8, 32, 3), 256, 0, stream>>>(abf, wt, qb, kb, vt);
    attn    <<<dim3(SS / 64, BB * HH), 256, 0, stream>>>(qb, kb, vt, (const unsigned*)mbits, ctx);
    gemm_out<<<dim3(8, 64), 256, 0, stream>>>(ctx, wt + 3 * WSZ, Qin, (float*)d_out);
}

// Round 10
// 293.306 us; speedup vs baseline: 1.1215x; 1.1215x over previous
//
#include <hip/hip_runtime.h>
#include <hip/hip_bf16.h>

// B=2, S=2048, IN=1024, H=16, D=64 MHA forward.
// wconv ; maskpack ; cvt3 ; gemm_qkv (gld16 staging) ; attn (single-buf K/V,
// gld16+XOR-swizzle, no-max softmax, ones-MFMA rowsum, bitmask) ; gemm_out.

#define BB   2
#define SS   2048
#define IND  1024
#define HH   16
#define DD   64
#define MM_ELEMS 524288   // 4096*1024/8 eight-element chunks per tensor

typedef __attribute__((ext_vector_type(8))) short  s8b;    // 8 x bf16 MFMA A/B frag
typedef __attribute__((ext_vector_type(4))) short  s4b;    // 4 x bf16
typedef __attribute__((ext_vector_type(4))) float  f32x4;  // MFMA C/D frag

static __device__ __forceinline__ short f2b(float x) {
    return __builtin_bit_cast(short, __float2bfloat16(x));
}

// async global->LDS, 16B per lane; LDS dest = base + lane*16 (wave-uniform base)
#define GLD16(g, l)                                                             \
    __builtin_amdgcn_global_load_lds(                                           \
        (const __attribute__((address_space(1))) unsigned int*)(g),             \
        (__attribute__((address_space(3))) unsigned int*)(l), 16, 0, 0)

// ---------------------------------------------------------------------------
// Kernel 1: weights fp32 [K][N] -> bf16 W^T [N][K].  z==0 (Wq) scaled by 1/8.
// ---------------------------------------------------------------------------
__global__ __launch_bounds__(256) void wconv(const float* __restrict__ w0,
                                             const float* __restrict__ w1,
                                             const float* __restrict__ w2,
                                             const float* __restrict__ w3,
                                             short* __restrict__ out) {
    const int z = blockIdx.z;
    const float* src = (z == 0) ? w0 : (z == 1) ? w1 : (z == 2) ? w2 : w3;
    const float wscale = (z == 0) ? 0.125f : 1.0f;
    short* dst = out + (size_t)z * IND * IND;
    __shared__ __attribute__((aligned(16))) short ls[64][72];
    const int t  = threadIdx.x;
    const int k0 = blockIdx.y * 64;
    const int n0 = blockIdx.x * 64;
#pragma unroll
    for (int p = 0; p < 4; ++p) {
        int ch = t + p * 256;
        int r  = ch >> 4;
        int c4 = ch & 15;
        float4 v = *reinterpret_cast<const float4*>(&src[(size_t)(k0 + r) * IND + n0 + c4 * 4]);
        ls[r][c4 * 4 + 0] = f2b(v.x * wscale);
        ls[r][c4 * 4 + 1] = f2b(v.y * wscale);
        ls[r][c4 * 4 + 2] = f2b(v.z * wscale);
        ls[r][c4 * 4 + 3] = f2b(v.w * wscale);
    }
    __syncthreads();
#pragma unroll
    for (int p = 0; p < 2; ++p) {
        int ch = t + p * 256;
        int nr = ch >> 3;
        int kg = ch & 7;
        s8b o;
#pragma unroll
        for (int j = 0; j < 8; ++j) o[j] = ls[kg * 8 + j][nr];
        *reinterpret_cast<s8b*>(&dst[(size_t)(n0 + nr) * IND + k0 + kg * 8]) = o;
    }
}

// ---------------------------------------------------------------------------
// Kernel 2: pack mask [B,S,S] (bool or int32, runtime-detected) into bits.
// ---------------------------------------------------------------------------
__global__ __launch_bounds__(256) void maskpack(const unsigned char* __restrict__ mask,
                                                unsigned long long* __restrict__ bits) {
    __shared__ int s_flag;
    const int t = threadIdx.x;
    if (t == 0) s_flag = 0;
    __syncthreads();
    {
        int bad = 0;
#pragma unroll
        for (int i = 0; i < 16; ++i) {
            int idx = t * 16 + i;
            if ((idx & 3) && mask[idx]) bad = 1;
        }
        if (bad) s_flag = 1;
    }
    __syncthreads();
    const bool isI32 = (s_flag == 0);

    const int lane = t & 63;
    const size_t nwords = (size_t)BB * SS * SS / 64;            // 131072
    size_t w = (size_t)blockIdx.x * 4 + (t >> 6);
    const size_t stride = (size_t)gridDim.x * 4;
    if (isI32) {
        const unsigned* m4 = (const unsigned*)mask;
        for (; w < nwords; w += stride) {
            unsigned long long bal = __ballot(m4[w * 64 + lane] != 0);
            if (lane == 0) bits[w] = bal;
        }
    } else {
        for (; w < nwords; w += stride) {
            unsigned long long bal = __ballot(mask[w * 64 + lane] != 0);
            if (lane == 0) bits[w] = bal;
        }
    }
}

// ---------------------------------------------------------------------------
// Kernel 2b: Q,K,V fp32 -> bf16 [3][4096][1024] (one pass, vectorized).
// ---------------------------------------------------------------------------
__global__ __launch_bounds__(256) void cvt3(const float* __restrict__ q,
                                            const float* __restrict__ k,
                                            const float* __restrict__ v,
                                            short* __restrict__ o) {
    const size_t nchunk = (size_t)3 * MM_ELEMS;
    size_t i = (size_t)blockIdx.x * 256 + threadIdx.x;
    const size_t stride = (size_t)gridDim.x * 256;
    for (; i < nchunk; i += stride) {
        size_t base = i * 8;
        int z = (int)(base >> 22);                       // 4M elems per tensor
        size_t off = base & 4194303u;
        const float* src = (z == 0) ? q : (z == 1) ? k : v;
        float4 a = *reinterpret_cast<const float4*>(&src[off]);
        float4 b = *reinterpret_cast<const float4*>(&src[off + 4]);
        s8b w;
        w[0] = f2b(a.x); w[1] = f2b(a.y); w[2] = f2b(a.z); w[3] = f2b(a.w);
        w[4] = f2b(b.x); w[5] = f2b(b.y); w[6] = f2b(b.z); w[7] = f2b(b.w);
        *reinterpret_cast<s8b*>(&o[base]) = w;
    }
}

// ---------------------------------------------------------------------------
// Kernel 3: fused QKV projection GEMM (all-bf16, gld16 staging).  grid (8,32,3).
// C[4096][1024] = A * Wt^T ; z<2 -> bf16 [B,H,S,D] (q,k) ; z==2 -> [B,H,D,S] (v).
// LDS: linear [128][32] per operand; 4 x GLD16 per wave per K-step (m97 style).
// ---------------------------------------------------------------------------
__global__ __launch_bounds__(256) void gemm_qkv(const short* __restrict__ abf,
                                                const short* __restrict__ wt,
                                                short* __restrict__ qb,
                                                short* __restrict__ kb,
                                                short* __restrict__ vt) {
    __shared__ __attribute__((aligned(16))) short lsA[128 * 32];
    __shared__ __attribute__((aligned(16))) short lsB[128 * 32];
    const int z = blockIdx.z;
    const short* A  = abf + (size_t)z * 4194304;
    const short* Bt = wt + (size_t)z * IND * IND;

    const int t    = threadIdx.x;
    const int lane = t & 63;
    const int wv   = t >> 6;
    const int wr   = wv >> 1, wc = wv & 1;
    const int m0   = blockIdx.y * 128, n0 = blockIdx.x * 128;
    const int lr   = lane & 15;
    const int lg   = lane >> 4;
    const int rs   = lane >> 2;   // row within 16-row chunk
    const int cs   = lane & 3;    // 16B slot within 64B row

    f32x4 acc[4][4] = {};

    for (int k0 = 0; k0 < IND; k0 += 32) {
        __syncthreads();   // previous iteration's frag reads done
        // stage A,B tiles: wave wv covers 16-row chunks {wv, wv+4} of each
        GLD16(&A [(size_t)(m0 + wv * 16      + rs) * IND + k0 + cs * 8], &lsA[ wv      * 512]);
        GLD16(&A [(size_t)(m0 + (wv+4) * 16  + rs) * IND + k0 + cs * 8], &lsA[(wv + 4) * 512]);
        GLD16(&Bt[(size_t)(n0 + wv * 16      + rs) * IND + k0 + cs * 8], &lsB[ wv      * 512]);
        GLD16(&Bt[(size_t)(n0 + (wv+4) * 16  + rs) * IND + k0 + cs * 8], &lsB[(wv + 4) * 512]);
        __syncthreads();   // drains vmcnt -> tiles ready

        s8b af[4], bfr[4];
#pragma unroll
        for (int mi = 0; mi < 4; ++mi)
            af[mi] = *reinterpret_cast<const s8b*>(&lsA[(wr * 64 + mi * 16 + lr) * 32 + lg * 8]);
#pragma unroll
        for (int nj = 0; nj < 4; ++nj)
            bfr[nj] = *reinterpret_cast<const s8b*>(&lsB[(wc * 64 + nj * 16 + lr) * 32 + lg * 8]);
#pragma unroll
        for (int mi = 0; mi < 4; ++mi)
#pragma unroll
            for (int nj = 0; nj < 4; ++nj)
                acc[mi][nj] = __builtin_amdgcn_mfma_f32_16x16x32_bf16(af[mi], bfr[nj], acc[mi][nj], 0, 0, 0);
    }

#pragma unroll
    for (int mi = 0; mi < 4; ++mi) {
#pragma unroll
        for (int nj = 0; nj < 4; ++nj) {
            const int mbase = m0 + wr * 64 + mi * 16 + lg * 4;
            const int n     = n0 + wc * 64 + nj * 16 + lr;
            if (z < 2) {
                short* o = z ? kb : qb;
                const int h = n >> 6, d = n & 63;
#pragma unroll
                for (int i = 0; i < 4; ++i) {
                    int m = mbase + i;
                    int b = m >> 11, s = m & 2047;
                    o[((size_t)(b * HH + h) * SS + s) * DD + d] = f2b(acc[mi][nj][i]);
                }
            } else {
                const int b = mbase >> 11, sbase = mbase & 2047;
                const int h = n >> 6, d = n & 63;
                s4b w;
#pragma unroll
                for (int i = 0; i < 4; ++i) w[i] = f2b(acc[mi][nj][i]);
                *reinterpret_cast<s4b*>(&vt[((size_t)(b * HH + h) * DD + d) * SS + sbase]) = w;
            }
        }
    }
}

// ---------------------------------------------------------------------------
// Kernel 4: flash attention.  grid (S/64, B*H), 4 waves x 16 q-rows, KV 64.
// SINGLE-buffered K/V (25.6 KB total LDS -> 6 blocks/CU) staged via gld16
// into linear [64][64] with XOR-swizzle (conflict-free); 2 barriers/tile,
// next-tile prefetch issued after the read-done barrier.
// No-max softmax (scale folded into Wq); rowsum via ones-MFMA; bitmask.
// ---------------------------------------------------------------------------
__global__ __launch_bounds__(256) void attn(const short* __restrict__ qb,
                                            const short* __restrict__ kb,
                                            const short* __restrict__ vt,
                                            const unsigned* __restrict__ mbw,
                                            short* __restrict__ ctx) {
    __shared__ __attribute__((aligned(16))) short lsK[64 * 64];
    __shared__ __attribute__((aligned(16))) short lsV[64 * 64];
    __shared__ __attribute__((aligned(16))) short lsP[4][16 * 72];

    const int t    = threadIdx.x;
    const int lane = t & 63;
    const int wv   = t >> 6;
    const int bh   = blockIdx.y;
    const int b    = bh >> 4, h = bh & 15;
    const int q0   = blockIdx.x * 64 + wv * 16;
    const int lr   = lane & 15;
    const int lg   = lane >> 4;

    const unsigned sel0 = 1u << lr;
    const unsigned sel1 = sel0 << 16;
    const uint2* mrp = (const uint2*)(mbw + (size_t)(b * SS + q0 + lg * 4) * (SS / 32));

    // staging geometry: lane -> row rk, swizzled source slot ck
    const int rk = lane >> 3;                 // 0..7
    const int ck = (lane & 7) ^ rk;           // pre-swizzled global column slot
    const short* kbase = kb + (size_t)bh * SS * DD;
    const short* vbase = vt + (size_t)bh * DD * SS;

    s8b aq[2];
#pragma unroll
    for (int ks = 0; ks < 2; ++ks)
        aq[ks] = *reinterpret_cast<const s8b*>(&qb[((size_t)bh * SS + q0 + lr) * DD + ks * 32 + lg * 8]);

    s8b ones;
#pragma unroll
    for (int j = 0; j < 8; ++j) ones[j] = (short)0x3F80;   // bf16 1.0

    f32x4 o[4] = {};
    float lrow[4] = {0.f, 0.f, 0.f, 0.f};

    // prologue: stage tile 0 (each wave: 2 K-chunks + 2 V-chunks of 8 rows)
#pragma unroll
    for (int c = 0; c < 2; ++c) {
        int chunk = wv + c * 4;               // 0..7
        int row = chunk * 8 + rk;
        GLD16(&kbase[(size_t)row * DD + ck * 8], &lsK[chunk * 512]);
        GLD16(&vbase[(size_t)row * SS + ck * 8], &lsV[chunk * 512]);
    }

    for (int kk0 = 0; kk0 < SS; kk0 += 64) {
        uint2 mw[4];
#pragma unroll
        for (int i = 0; i < 4; ++i) mw[i] = mrp[i * 32 + (kk0 >> 6)];

        __syncthreads();   // drains vmcnt -> K/V tile ready

        // S = Q K^T (pre-scaled); swizzled B-frag reads (conflict-free)
        f32x4 sc[4];
#pragma unroll
        for (int nj = 0; nj < 4; ++nj) {
            const int R  = nj * 16 + lr;
            const int sw = R & 7;
            s8b bk0 = *reinterpret_cast<const s8b*>(&lsK[R * 64 + ((lg ^ sw) << 3)]);
            s8b bk1 = *reinterpret_cast<const s8b*>(&lsK[R * 64 + (((lg ^ 4) ^ sw) << 3)]);
            f32x4 zz = {};
            zz     = __builtin_amdgcn_mfma_f32_16x16x32_bf16(aq[0], bk0, zz, 0, 0, 0);
            sc[nj] = __builtin_amdgcn_mfma_f32_16x16x32_bf16(aq[1], bk1, zz, 0, 0, 0);
        }

        // P = masked ? 0 : exp(S) -> per-wave LDS
#pragma unroll
        for (int nj = 0; nj < 4; ++nj) {
            const unsigned slm = (nj & 1) ? sel1 : sel0;
#pragma unroll
            for (int i = 0; i < 4; ++i) {
                unsigned w = (nj < 2) ? mw[i].x : mw[i].y;
                float e = __expf(sc[nj][i]);
                float p = (w & slm) ? 0.f : e;
                lsP[wv][(lg * 4 + i) * 72 + nj * 16 + lr] = f2b(p);
            }
        }

        s8b pa[2];
#pragma unroll
        for (int ks = 0; ks < 2; ++ks)
            pa[ks] = *reinterpret_cast<const s8b*>(&lsP[wv][lr * 72 + ks * 32 + lg * 8]);

        // row-sum of P via ones-MFMA
        f32x4 rs = {};
        rs = __builtin_amdgcn_mfma_f32_16x16x32_bf16(pa[0], ones, rs, 0, 0, 0);
        rs = __builtin_amdgcn_mfma_f32_16x16x32_bf16(pa[1], ones, rs, 0, 0, 0);

#pragma unroll
        for (int nj = 0; nj < 4; ++nj) {
            const int R  = nj * 16 + lr;
            const int sw = R & 7;
            s8b bv0 = *reinterpret_cast<const s8b*>(&lsV[R * 64 + ((lg ^ sw) << 3)]);
            s8b bv1 = *reinterpret_cast<const s8b*>(&lsV[R * 64 + (((lg ^ 4) ^ sw) << 3)]);
            o[nj] = __builtin_amdgcn_mfma_f32_16x16x32_bf16(pa[0], bv0, o[nj], 0, 0, 0);
            o[nj] = __builtin_amdgcn_mfma_f32_16x16x32_bf16(pa[1], bv1, o[nj], 0, 0, 0);
        }
#pragma unroll
        for (int i = 0; i < 4; ++i) lrow[i] += rs[i];

        __syncthreads();   // all waves done reading K/V -> safe to overwrite

        if (kk0 + 64 < SS) {
#pragma unroll
            for (int c = 0; c < 2; ++c) {
                int chunk = wv + c * 4;
                int row = chunk * 8 + rk;
                GLD16(&kbase[(size_t)(kk0 + 64 + row) * DD + ck * 8], &lsK[chunk * 512]);
                GLD16(&vbase[(size_t)row * SS + kk0 + 64 + ck * 8], &lsV[chunk * 512]);
            }
        }
    }

    float inv[4];
#pragma unroll
    for (int i = 0; i < 4; ++i) inv[i] = 1.0f / lrow[i];
#pragma unroll
    for (int nj = 0; nj < 4; ++nj)
#pragma unroll
        for (int i = 0; i < 4; ++i) {
            int q = q0 + lg * 4 + i;
            ctx[((size_t)(b * SS + q)) * (HH * DD) + h * DD + nj * 16 + lr] = f2b(o[nj][i] * inv[i]);
        }
}

// ---------------------------------------------------------------------------
// Kernel 5: out = ctx @ Wo^T + Q.  64x128 tile, gld16 staging, 2x4 frags.
// ---------------------------------------------------------------------------
__global__ __launch_bounds__(256) void gemm_out(const short* __restrict__ Actx,
                                                const short* __restrict__ Bt,
                                                const float* __restrict__ resid,
                                                float* __restrict__ outp) {
    __shared__ __attribute__((aligned(16))) short lsA[64 * 32];
    __shared__ __attribute__((aligned(16))) short lsB[128 * 32];
    const int t    = threadIdx.x;
    const int lane = t & 63;
    const int wv   = t >> 6;
    const int wr   = wv >> 1, wc = wv & 1;
    const int m0   = blockIdx.y * 64, n0 = blockIdx.x * 128;
    const int lr   = lane & 15;
    const int lg   = lane >> 4;
    const int rs   = lane >> 2;
    const int cs   = lane & 3;

    f32x4 acc[2][4] = {};

    for (int k0 = 0; k0 < IND; k0 += 32) {
        __syncthreads();
        GLD16(&Actx[(size_t)(m0 + wv * 16     + rs) * IND + k0 + cs * 8], &lsA[ wv      * 512]);
        GLD16(&Bt  [(size_t)(n0 + wv * 16     + rs) * IND + k0 + cs * 8], &lsB[ wv      * 512]);
        GLD16(&Bt  [(size_t)(n0 + (wv+4) * 16 + rs) * IND + k0 + cs * 8], &lsB[(wv + 4) * 512]);
        __syncthreads();

        s8b af[2], bfr[4];
#pragma unroll
        for (int mi = 0; mi < 2; ++mi)
            af[mi] = *reinterpret_cast<const s8b*>(&lsA[(wr * 32 + mi * 16 + lr) * 32 + lg * 8]);
#pragma unroll
        for (int nj = 0; nj < 4; ++nj)
            bfr[nj] = *reinterpret_cast<const s8b*>(&lsB[(wc * 64 + nj * 16 + lr) * 32 + lg * 8]);
#pragma unroll
        for (int mi = 0; mi < 2; ++mi)
#pragma unroll
            for (int nj = 0; nj < 4; ++nj)
                acc[mi][nj] = __builtin_amdgcn_mfma_f32_16x16x32_bf16(af[mi], bfr[nj], acc[mi][nj], 0, 0, 0);
    }

#pragma unroll
    for (int mi = 0; mi < 2; ++mi)
#pragma unroll
        for (int nj = 0; nj < 4; ++nj) {
            const int mbase = m0 + wr * 32 + mi * 16 + lg * 4;
            const int n     = n0 + wc * 64 + nj * 16 + lr;
#pragma unroll
            for (int i = 0; i < 4; ++i) {
                int m = mbase + i;
                outp[(size_t)m * IND + n] = acc[mi][nj][i] + resid[(size_t)m * IND + n];
            }
        }
}

// ---------------------------------------------------------------------------
extern "C" void kernel_launch(void* const* d_in, const int* in_sizes, int n_in,
                              void* d_out, int out_size, void* d_ws, size_t ws_size,
                              hipStream_t stream) {
    const float* Qin = (const float*)d_in[0];
    const float* Kin = (const float*)d_in[1];
    const float* Vin = (const float*)d_in[2];
    const unsigned char* mask = (const unsigned char*)d_in[3];
    const float* Wq = (const float*)d_in[4];
    const float* Wk = (const float*)d_in[5];
    const float* Wv = (const float*)d_in[6];
    const float* Wo = (const float*)d_in[7];

    char* ws = (char*)d_ws;
    const size_t WSZ = (size_t)IND * IND;
    short* wt  = (short*)ws;                                       // 8 MB (4x W^T bf16)
    short* qb  = (short*)(ws + 8ull  * 1024 * 1024);               // [B,H,S,D]
    short* kb  = (short*)(ws + 16ull * 1024 * 1024);               // [B,H,S,D]
    short* vt  = (short*)(ws + 24ull * 1024 * 1024);               // [B,H,D,S]
    unsigned long long* mbits = (unsigned long long*)(ws + 32ull * 1024 * 1024);  // 1 MB
    short* abf = (short*)(ws + 36ull * 1024 * 1024);               // 24 MB bf16 QKV inputs
    short* ctx = (short*)(ws + 36ull * 1024 * 1024);               // overlaps abf (abf dead when attn writes ctx)

    wconv   <<<dim3(16, 16, 4), 256, 0, stream>>>(Wq, Wk, Wv, Wo, wt);
    maskpack<<<512, 256, 0, stream>>>(mask, mbits);
    cvt3    <<<2048, 256, 0, stream>>>(Qin, Kin, Vin, abf);
    gemm_qkv<<<dim3(8, 32, 3), 256, 0, stream>>>(abf, wt, qb, kb, vt);
    attn    <<<dim3(SS / 64, BB * HH), 256, 0, stream>>>(qb, kb, vt, (const unsigned*)mbits, ctx);
    gemm_out<<<dim3(8, 64), 256, 0, stream>>>(ctx, wt + 3 * WSZ, Qin, (float*)d_out);
}